// Round 3
// baseline (495.176 us; speedup 1.0000x reference)
//
#include <hip/hip_runtime.h>

// Euler-Maruyama as a parallel prefix-product (persistent, pipelined):
//   Z[b,i] = Z0[b] * prod_{j=1..i} (1 + r*dt + s*sqrt(dt)*W[b,j])
// 4096 blocks x 256 threads; each block owns 32 contiguous rows and
// software-pipelines: row r+1 loads issue before row r's scan+stores, so
// HBM reads stay in flight across the barrier. One __syncthreads per row
// via double-buffered wave-total LDS. Nontemporal hints on all streams.
// Output tuple (Z, W): d_out = [Z (B*1025 f32), verbatim W copy].

__global__ __launch_bounds__(256) void em_prefix_kernel(
    const float* __restrict__ Z0,
    const float* __restrict__ W,
    const float* __restrict__ Wf,
    const float* __restrict__ Wg,
    float* __restrict__ Zout,
    float* __restrict__ Wout,
    int B, int rowsPerBlock)
{
    constexpr int NP1  = 1025;
    constexpr int SEG  = 256;   // elements per segment == threads per block
    constexpr int NSEG = 4;     // 4*256 = 1024 scan steps

    const int t    = threadIdx.x;
    const int lane = t & 63;
    const int wid  = t >> 6;

    const float dt  = 1.0f / 1024.0f;   // exact
    const float sdt = 0.03125f;         // sqrt(1/1024), exact
    const float a   = Wf[0] * dt;
    const float c   = Wg[0] * sdt;
    const float m0  = 1.0f + a;

    __shared__ float wtot[2][NSEG][4];  // double-buffered per-wave totals

    const int r0 = blockIdx.x * rowsPerBlock;
    const int r1 = min(r0 + rowsPerBlock, B);
    if (r0 >= r1) return;

    // Prologue: load first row's W values (coalesced 4B/lane, nontemporal).
    float wcur[NSEG];
    {
        const float* __restrict__ wrow = W + (size_t)r0 * NP1;
        #pragma unroll
        for (int s = 0; s < NSEG; ++s)
            wcur[s] = __builtin_nontemporal_load(wrow + 1 + s * SEG + t);
    }

    int parity = 0;
    for (int r = r0; r < r1; ++r) {
        // Issue next row's loads NOW; vmcnt wait lands after the scan below.
        float wnxt[NSEG];
        const bool havenext = (r + 1 < r1);
        if (havenext) {
            const float* __restrict__ wrown = W + (size_t)(r + 1) * NP1;
            #pragma unroll
            for (int s = 0; s < NSEG; ++s)
                wnxt[s] = __builtin_nontemporal_load(wrown + 1 + s * SEG + t);
        }

        // Wave-level inclusive product scan per segment.
        float p[NSEG];
        #pragma unroll
        for (int s = 0; s < NSEG; ++s) {
            float v = fmaf(c, wcur[s], m0);
            #pragma unroll
            for (int d = 1; d < 64; d <<= 1) {
                float o = __shfl_up(v, d, 64);
                if (lane >= d) v *= o;
            }
            p[s] = v;
            if (lane == 63) wtot[parity][s][wid] = v;
        }
        __syncthreads();

        const float  z0   = Z0[r];                // block-uniform -> s_load
        const size_t base = (size_t)r * NP1;
        if (t == 0) {
            __builtin_nontemporal_store(z0, Zout + base);
            __builtin_nontemporal_store(W[base], Wout + base);  // W[:,0] copy
        }

        // Cross-wave + cross-segment combine, then coalesced stores.
        float C = z0;
        #pragma unroll
        for (int s = 0; s < NSEG; ++s) {
            float wpre = 1.0f;
            #pragma unroll
            for (int wv = 0; wv < 3; ++wv) {
                float tv = wtot[parity][s][wv];
                if (wv < wid) wpre *= tv;
            }
            const int idx = 1 + s * SEG + t;
            __builtin_nontemporal_store(C * wpre * p[s], Zout + base + idx);
            __builtin_nontemporal_store(wcur[s],        Wout + base + idx);
            C *= wtot[parity][s][0] * wtot[parity][s][1]
               * wtot[parity][s][2] * wtot[parity][s][3];
        }

        if (havenext) {
            #pragma unroll
            for (int s = 0; s < NSEG; ++s) wcur[s] = wnxt[s];
        }
        parity ^= 1;
    }
}

extern "C" void kernel_launch(void* const* d_in, const int* in_sizes, int n_in,
                              void* d_out, int out_size, void* d_ws, size_t ws_size,
                              hipStream_t stream) {
    const float* Z0 = (const float*)d_in[0];
    const float* W  = (const float*)d_in[1];
    const float* Wf = (const float*)d_in[2];
    const float* Wg = (const float*)d_in[3];

    const int B   = in_sizes[0];              // 131072
    const int NP1 = in_sizes[1] / B;          // 1025
    (void)NP1;

    float* Zout = (float*)d_out;
    float* Wout = Zout + (size_t)B * (size_t)NP1;

    const int blocks = 4096;                  // contiguous-chunk persistent-ish grid
    const int rpb    = (B + blocks - 1) / blocks;   // 32
    em_prefix_kernel<<<blocks, 256, 0, stream>>>(Z0, W, Wf, Wg, Zout, Wout, B, rpb);
}

// Round 4
// 325.540 us; speedup vs baseline: 1.5211x; 1.5211x over previous
//
#include <hip/hip_runtime.h>

// Euler-Maruyama as a parallel prefix-product, wave-autonomous:
//   Z[b,i] = Z0[b] * prod_{j=1..i} (1 + r*dt + s*sqrt(dt)*W[b,j])
// One row per WAVE (4 rows per 256-thread block, 32768 blocks). No LDS, no
// __syncthreads -> no barrier tail-latency amplification; each wave streams
// as soon as its own loads land. Row = 16 chunks of 64; per-chunk 6-step
// __shfl_up product scan (16 independent scans = ILP), serial lane-63
// broadcast carry across chunks. W-copy stores issue BEFORE the scan so the
// memory pipe stays busy during VALU work.
// Output tuple (Z, W): d_out = [Z (B*1025 f32), verbatim W copy].

__global__ __launch_bounds__(256) void em_wave_kernel(
    const float* __restrict__ Z0,
    const float* __restrict__ W,
    const float* __restrict__ Wf,
    const float* __restrict__ Wg,
    float* __restrict__ Zout,
    float* __restrict__ Wout,
    int B)
{
    constexpr int NP1 = 1025;
    constexpr int NCH = 16;     // 16 chunks x 64 lanes = 1024 scan steps

    const int lane = threadIdx.x & 63;
    const int wid  = threadIdx.x >> 6;
    const int r    = blockIdx.x * 4 + wid;
    if (r >= B) return;

    const float dt  = 1.0f / 1024.0f;   // exact
    const float sdt = 0.03125f;         // sqrt(1/1024), exact
    const float a   = Wf[0] * dt;
    const float c   = Wg[0] * sdt;
    const float m0  = 1.0f + a;

    const size_t base = (size_t)r * NP1;
    const float* __restrict__ wrow  = W    + base;
    float*       __restrict__ zrow  = Zout + base;
    float*       __restrict__ worow = Wout + base;

    // Coalesced loads: chunk k = elements [1+64k, 64+64k], 4B/lane dense.
    float w[NCH];
    #pragma unroll
    for (int k = 0; k < NCH; ++k)
        w[k] = wrow[1 + 64 * k + lane];

    // W-copy stores issued immediately (independent of the scan) so the
    // memory system has work while the VALU does the scans.
    #pragma unroll
    for (int k = 0; k < NCH; ++k)
        worow[1 + 64 * k + lane] = w[k];

    const float z0 = Z0[r];             // wave-uniform -> scalar load
    if (lane == 0) {
        zrow[0]  = z0;
        worow[0] = wrow[0];             // W[:,0] unused by scan, copied
    }

    // 16 independent wave-level inclusive product scans.
    float p[NCH];
    #pragma unroll
    for (int k = 0; k < NCH; ++k) {
        float v = fmaf(c, w[k], m0);
        #pragma unroll
        for (int d = 1; d < 64; d <<= 1) {
            float o = __shfl_up(v, d, 64);
            if (lane >= d) v *= o;
        }
        p[k] = v;
    }

    // Serial carry across chunks (lane-63 broadcast) + coalesced Z stores.
    float carry = z0;
    #pragma unroll
    for (int k = 0; k < NCH; ++k) {
        zrow[1 + 64 * k + lane] = carry * p[k];
        carry *= __shfl(p[k], 63, 64);
    }
}

extern "C" void kernel_launch(void* const* d_in, const int* in_sizes, int n_in,
                              void* d_out, int out_size, void* d_ws, size_t ws_size,
                              hipStream_t stream) {
    const float* Z0 = (const float*)d_in[0];
    const float* W  = (const float*)d_in[1];
    const float* Wf = (const float*)d_in[2];
    const float* Wg = (const float*)d_in[3];

    const int B   = in_sizes[0];              // 131072
    const int NP1 = in_sizes[1] / B;          // 1025
    (void)NP1;

    float* Zout = (float*)d_out;
    float* Wout = Zout + (size_t)B * 1025;

    const int rowsPerBlock = 4;               // one row per wave
    const int blocks = (B + rowsPerBlock - 1) / rowsPerBlock;   // 32768
    em_wave_kernel<<<blocks, 256, 0, stream>>>(Z0, W, Wf, Wg, Zout, Wout, B);
}

// Round 5
// 286.753 us; speedup vs baseline: 1.7268x; 1.1353x over previous
//
#include <hip/hip_runtime.h>

// Euler-Maruyama prefix-product, float4 edition.
//   Z[b,i] = Z0[b] * prod_{j=1..i} (1 + r*dt + s*sqrt(dt)*W[b,j])
// One 256-thread block per row. Thread t owns 4 CONTIGUOUS elements
// (aligned float4 #t of the row body): local serial product (3 muls), then a
// wave scan over the 256 per-thread products (6 shfls) + LDS cross-wave
// combine -> DS-pipe work drops 3x vs per-element scan, and ALL bulk
// loads/stores are aligned float4 (16B/lane).
// Rows start at base+1 ((r+1)&3 misaligned): block-uniform scalar head
// (folded into the carry) + aligned body + scalar tail on thread 255.
// XCD-chunked row swizzle keeps row-boundary cache lines in one L2.
// Output tuple (Z, W): d_out = [Z (B*1025 f32), verbatim W copy].

__global__ __launch_bounds__(256) void em_f4_kernel(
    const float* __restrict__ Z0,
    const float* __restrict__ W,
    const float* __restrict__ Wf,
    const float* __restrict__ Wg,
    float* __restrict__ Zout,
    float* __restrict__ Wout,
    int B)
{
    constexpr int NP1 = 1025;
    const int t    = threadIdx.x;
    const int lane = t & 63;
    const int wid  = t >> 6;

    // XCD-chunked bijective swizzle (8 XCDs, B % 8 == 0): consecutive rows
    // (which share boundary 128B lines) stay on the same XCD's L2.
    const int nper = B >> 3;
    const int bid  = (int)blockIdx.x;
    const int r    = (bid & 7) * nper + (bid >> 3);

    const float dt  = 1.0f / 1024.0f;   // exact
    const float sdt = 0.03125f;         // sqrt(1/1024), exact
    const float a   = Wf[0] * dt;
    const float c   = Wg[0] * sdt;
    const float m0  = 1.0f + a;

    const size_t base = (size_t)r * NP1;
    const float* __restrict__ wrow  = W    + base;
    float*       __restrict__ zrow  = Zout + base;
    float*       __restrict__ worow = Wout + base;

    // Row scan body = indices 1..1024. (base+1) % 4 == (r+1) & 3.
    const int h    = (4 - ((r + 1) & 3)) & 3;  // scalar head count (0..3)
    const int nv   = (1024 - h) >> 2;          // full float4s: 256 (h==0) or 255
    const int tail = 1024 - h - (nv << 2);     // 0 (h==0) or 4-h

    // Head multipliers (row idx 1..h), computed redundantly by all threads
    // (broadcast loads); folded into the block carry.
    float wh0 = 0.f, wh1 = 0.f, wh2 = 0.f;
    float headprod = 1.0f;
    if (h > 0) { wh0 = wrow[1]; headprod *= fmaf(c, wh0, m0); }
    if (h > 1) { wh1 = wrow[2]; headprod *= fmaf(c, wh1, m0); }
    if (h > 2) { wh2 = wrow[3]; headprod *= fmaf(c, wh2, m0); }

    // Per-thread slot: t < nv -> float4 #t (row idx 1+h+4t ..+3);
    // t >= nv (only t==255 when h>0) -> the tail scalars.
    const bool isvec = (t < nv);
    float4 wq = make_float4(0.f, 0.f, 0.f, 0.f);
    float tw0 = 0.f, tw1 = 0.f, tw2 = 0.f;
    float m1 = 1.f, m2 = 1.f, m3 = 1.f, m4 = 1.f;
    const int i0 = 1 + h + (nv << 2);          // first tail row-index
    if (isvec) {
        const float4* __restrict__ wv =
            reinterpret_cast<const float4*>(wrow + 1 + h);
        wq = wv[t];
        m1 = fmaf(c, wq.x, m0);
        m2 = fmaf(c, wq.y, m0);
        m3 = fmaf(c, wq.z, m0);
        m4 = fmaf(c, wq.w, m0);
    } else {
        if (tail > 0) { tw0 = wrow[i0 + 0]; m1 = fmaf(c, tw0, m0); }
        if (tail > 1) { tw1 = wrow[i0 + 1]; m2 = fmaf(c, tw1, m0); }
        if (tail > 2) { tw2 = wrow[i0 + 2]; m3 = fmaf(c, tw2, m0); }
    }
    float prod = (m1 * m2) * (m3 * m4);

    // Wave-level inclusive scan over the 256 per-thread products.
    float p = prod;
    #pragma unroll
    for (int d = 1; d < 64; d <<= 1) {
        float o = __shfl_up(p, d, 64);
        if (lane >= d) p *= o;
    }

    __shared__ float wtot[4];
    if (lane == 63) wtot[wid] = p;
    __syncthreads();

    // Exclusive-within-wave + cross-wave prefix.
    float ep = __shfl_up(p, 1, 64);
    if (lane == 0) ep = 1.0f;
    float wpre = 1.0f;
    if (wid > 0) wpre *= wtot[0];
    if (wid > 1) wpre *= wtot[1];
    if (wid > 2) wpre *= wtot[2];

    const float z0 = Z0[r];                    // block-uniform -> scalar load

    if (t == 0) {
        zrow[0]  = z0;
        worow[0] = wrow[0];                    // W[:,0] copy
        float run = z0;
        if (h > 0) { run *= fmaf(c, wh0, m0); zrow[1] = run; worow[1] = wh0; }
        if (h > 1) { run *= fmaf(c, wh1, m0); zrow[2] = run; worow[2] = wh1; }
        if (h > 2) { run *= fmaf(c, wh2, m0); zrow[3] = run; worow[3] = wh2; }
    }

    // S = product of everything strictly before this thread's first element.
    const float S = ((z0 * headprod) * wpre) * ep;

    if (isvec) {
        float zx = S  * m1;
        float zy = zx * m2;
        float zz = zy * m3;
        float zw = zz * m4;
        float4* __restrict__ zv  = reinterpret_cast<float4*>(zrow  + 1 + h);
        float4* __restrict__ wov = reinterpret_cast<float4*>(worow + 1 + h);
        zv[t]  = make_float4(zx, zy, zz, zw);
        wov[t] = wq;
    } else {
        float run = S;
        if (tail > 0) { run *= m1; zrow[i0 + 0] = run; worow[i0 + 0] = tw0; }
        if (tail > 1) { run *= m2; zrow[i0 + 1] = run; worow[i0 + 1] = tw1; }
        if (tail > 2) { run *= m3; zrow[i0 + 2] = run; worow[i0 + 2] = tw2; }
    }
}

extern "C" void kernel_launch(void* const* d_in, const int* in_sizes, int n_in,
                              void* d_out, int out_size, void* d_ws, size_t ws_size,
                              hipStream_t stream) {
    const float* Z0 = (const float*)d_in[0];
    const float* W  = (const float*)d_in[1];
    const float* Wf = (const float*)d_in[2];
    const float* Wg = (const float*)d_in[3];

    const int B   = in_sizes[0];              // 131072
    const int NP1 = in_sizes[1] / B;          // 1025
    (void)NP1;

    float* Zout = (float*)d_out;
    float* Wout = Zout + (size_t)B * 1025;

    em_f4_kernel<<<B, 256, 0, stream>>>(Z0, W, Wf, Wg, Zout, Wout, B);
}